// Round 2
// baseline (1028.072 us; speedup 1.0000x reference)
//
#include <hip/hip_runtime.h>
#include <stdint.h>

// Problem constants (fixed by setup_inputs)
#define N_ROWS  32768
#define D_DIM   512
#define K_CODES 8192
#define BM 128
#define BN 128
#define BK 32
#define NTILES (K_CODES / BN)   // 64 code-tiles per row

typedef __attribute__((ext_vector_type(8))) short short8;
typedef __attribute__((ext_vector_type(4))) float f32x4;
typedef unsigned long long u64;
typedef unsigned int u32;
typedef unsigned short u16;

// ---------- helpers ----------

__device__ __forceinline__ u16 bf_rne(float f) {
    // round-to-nearest-even fp32 -> bf16 (inputs are finite)
    u32 u = __float_as_uint(f);
    u32 r = (u + 0x7FFFu + ((u >> 16) & 1u)) >> 16;
    return (u16)r;
}

__device__ __forceinline__ u32 fkey(float f) {
    // monotonic (order-preserving) float -> uint transform
    u32 u = __float_as_uint(f);
    return (u & 0x80000000u) ? ~u : (u | 0x80000000u);
}

__device__ __forceinline__ void top2_merge(u64 &a1, u64 &a2, u64 b1, u64 b2) {
    u64 lo = a1 < b1 ? a1 : b1;
    u64 hi = a1 < b1 ? b1 : a1;
    u64 c  = a2 < b2 ? a2 : b2;
    a1 = lo;
    a2 = hi < c ? hi : c;
}

__device__ __forceinline__ void gll16(const void* g, void* l) {
    // async global->LDS, 16B per lane; LDS dest = wave-uniform base + lane*16
    __builtin_amdgcn_global_load_lds((const __attribute__((address_space(1))) void*)g,
                                     (__attribute__((address_space(3))) void*)l,
                                     16, 0, 0);
}

// ---------- prep: fp32 -> (hi, lo) bf16 split (+ optional row sum-of-squares) ----------

__global__ __launch_bounds__(256) void prep_split(const float* __restrict__ src,
                                                  u16* __restrict__ hp,
                                                  u16* __restrict__ lp,
                                                  float* __restrict__ np) {
    int row  = blockIdx.x * 4 + (threadIdx.x >> 6);
    int lane = threadIdx.x & 63;
    const float* s = src + (size_t)row * D_DIM + lane * 8;
    float4 a = *(const float4*)(s);
    float4 b = *(const float4*)(s + 4);
    float v[8] = {a.x, a.y, a.z, a.w, b.x, b.y, b.z, b.w};
    short8 hv, lv;
    float sum = 0.f;
#pragma unroll
    for (int j = 0; j < 8; j++) {
        u16 h = bf_rne(v[j]);
        float fh = __uint_as_float(((u32)h) << 16);
        u16 l = bf_rne(v[j] - fh);
        hv[j] = (short)h;
        lv[j] = (short)l;
        sum += v[j] * v[j];
    }
    *(short8*)(hp + (size_t)row * D_DIM + lane * 8) = hv;
    *(short8*)(lp + (size_t)row * D_DIM + lane * 8) = lv;
    if (np != nullptr) {
#pragma unroll
        for (int mask = 1; mask < 64; mask <<= 1)
            sum += __shfl_xor(sum, mask, 64);
        if (lane == 0) np[row] = sum;
    }
}

// ---------- main: fused bf16x3 GEMM + per-row top-2 over this 128-code tile ----------
// dist_approx(i,j) = cnorm[j] - 2 * ( xh.ch + xh.cl + xl.ch )
// Each block: 128 rows x 128 codes, writes (min1,id1,min2,id2) packed u64x2 per row.

__global__ __launch_bounds__(256, 2) void qgemm(const u16* __restrict__ xh, const u16* __restrict__ xl,
                                                const u16* __restrict__ ch, const u16* __restrict__ cl,
                                                const float* __restrict__ cnorm,
                                                ulonglong2* __restrict__ tileres) {
    // LDS: Ah/Al/Bh/Bl each [128 rows][32 elems] bf16 = 8KB -> 32KB total.
    __shared__ char smem[32768];

    // XCD-aware swizzle (16384 blocks % 8 == 0 -> simple remap is bijective).
    // M fastest within an XCD chunk -> 8 codebook tiles (2MB hi+lo) stay L2-resident.
    int bid = blockIdx.x;
    int wg  = (bid & 7) * 2048 + (bid >> 3);
    int tileM = wg & 255;   // 0..255
    int tileN = wg >> 8;    // 0..63

    int tid  = threadIdx.x;
    int lane = tid & 63;
    int w    = tid >> 6;
    int wr   = w >> 1, wc = w & 1;   // wave -> 64x64 output quadrant

    f32x4 acc[4][4];
#pragma unroll
    for (int m = 0; m < 4; m++)
#pragma unroll
        for (int n = 0; n < 4; n++)
            acc[m][n] = (f32x4){0.f, 0.f, 0.f, 0.f};

    // Staging geometry: chunk q = tid + 256*i (i=0,1); row=q>>2; cin=q&3.
    // LDS is written LINEARLY (global_load_lds constraint); the XOR swizzle
    // (chunk ^= (row>>1)&3) is applied on the GLOBAL source address instead
    // (rule #21: both-sides-or-neither).  This swizzle makes the ds_read_b128
    // bank-quad index (row&1)*4 + chunk^((row>>1)&3) cover all 8 quads over
    // any 16 consecutive rows -> 2 lanes/quad = free (m136).
    size_t aoff[2], boff[2];
    int ldsq[2];
#pragma unroll
    for (int i = 0; i < 2; i++) {
        int q = tid + 256 * i;
        int row = q >> 2;
        int csw = (q & 3) ^ ((row >> 1) & 3);
        aoff[i] = ((size_t)(tileM * BM + row)) * D_DIM + csw * 8;
        boff[i] = ((size_t)(tileN * BN + row)) * D_DIM + csw * 8;
        ldsq[i] = (w * 64 + 256 * i) * 16;   // wave-uniform LDS byte base
    }

    for (int kk = 0; kk < D_DIM; kk += BK) {
#pragma unroll
        for (int i = 0; i < 2; i++) {
            gll16(xh + aoff[i] + kk, smem +     0 + ldsq[i]);
            gll16(xl + aoff[i] + kk, smem +  8192 + ldsq[i]);
            gll16(ch + boff[i] + kk, smem + 16384 + ldsq[i]);
            gll16(cl + boff[i] + kk, smem + 24576 + ldsq[i]);
        }
        __syncthreads();   // compiler drains vmcnt before s_barrier

        int colb = (lane >> 4) * 16;   // k-slice byte offset (8 bf16 per quad)
        short8 bh[4], bl[4];
#pragma unroll
        for (int n = 0; n < 4; n++) {
            int rb = wc * 64 + n * 16 + (lane & 15);
            int ad = rb * 64 + (colb ^ (((rb >> 1) & 3) << 4));
            bh[n] = *(const short8*)(smem + 16384 + ad);
            bl[n] = *(const short8*)(smem + 24576 + ad);
        }
#pragma unroll
        for (int m = 0; m < 4; m++) {
            int ra = wr * 64 + m * 16 + (lane & 15);
            int ad = ra * 64 + (colb ^ (((ra >> 1) & 3) << 4));
            short8 ah = *(const short8*)(smem +    0 + ad);
            short8 al = *(const short8*)(smem + 8192 + ad);
#pragma unroll
            for (int n = 0; n < 4; n++) {
                acc[m][n] = __builtin_amdgcn_mfma_f32_16x16x32_bf16(ah, bh[n], acc[m][n], 0, 0, 0);
                acc[m][n] = __builtin_amdgcn_mfma_f32_16x16x32_bf16(ah, bl[n], acc[m][n], 0, 0, 0);
                acc[m][n] = __builtin_amdgcn_mfma_f32_16x16x32_bf16(al, bh[n], acc[m][n], 0, 0, 0);
            }
        }
        __syncthreads();
    }

    // ---- epilogue: dist + per-row top-2 across the 128 codes of this tile ----
    int cq = lane >> 4, cc = lane & 15;
    float cn[4];
#pragma unroll
    for (int n = 0; n < 4; n++)
        cn[n] = cnorm[tileN * BN + wc * 64 + n * 16 + cc];

    u64* sc = (u64*)smem;   // scratch [128 rows][2 wc][2] = 4KB (staging is dead now)

#pragma unroll
    for (int m = 0; m < 4; m++) {
#pragma unroll
        for (int r = 0; r < 4; r++) {
            u64 k1 = ~0ull, k2 = ~0ull;
#pragma unroll
            for (int n = 0; n < 4; n++) {
                float d = cn[n] - 2.0f * acc[m][n][r];
                u64 key = ((u64)fkey(d) << 32) | (u32)(tileN * BN + wc * 64 + n * 16 + cc);
                if (key < k1) { k2 = k1; k1 = key; }
                else if (key < k2) { k2 = key; }
            }
            // reduce across the 16 lanes sharing this row (C/D: col=lane&15)
#pragma unroll
            for (int mask = 1; mask < 16; mask <<= 1) {
                u64 o1 = __shfl_xor((unsigned long long)k1, mask, 16);
                u64 o2 = __shfl_xor((unsigned long long)k2, mask, 16);
                top2_merge(k1, k2, o1, o2);
            }
            if (cc == 0) {
                int rl = wr * 64 + m * 16 + cq * 4 + r;   // C/D: row=(lane>>4)*4+reg
                sc[rl * 4 + wc * 2 + 0] = k1;
                sc[rl * 4 + wc * 2 + 1] = k2;
            }
        }
    }
    __syncthreads();
    if (tid < 128) {
        u64 a1 = sc[tid * 4 + 0], a2 = sc[tid * 4 + 1];
        u64 b1 = sc[tid * 4 + 2], b2 = sc[tid * 4 + 3];
        top2_merge(a1, a2, b1, b2);
        ulonglong2 outv;
        outv.x = a1;
        outv.y = a2;
        tileres[(size_t)(tileM * BM + tid) * NTILES + tileN] = outv;
    }
}

// ---------- finalize: global top-2 merge, exact fp32 re-rank of the 2 candidates,
//            gather emb (STE form), ids (as float), loss = 1.25 * ||x - emb||^2 ----------

__global__ __launch_bounds__(256) void finalize(const float* __restrict__ x, const float* __restrict__ cb,
                                                const ulonglong2* __restrict__ tileres,
                                                float* __restrict__ emb, float* __restrict__ idsf,
                                                float* __restrict__ lossf) {
    int row  = blockIdx.x * 4 + (threadIdx.x >> 6);
    int lane = threadIdx.x & 63;

    ulonglong2 t = tileres[(size_t)row * NTILES + lane];   // 64 tiles == 64 lanes
    u64 k1 = t.x, k2 = t.y;
#pragma unroll
    for (int mask = 1; mask < 64; mask <<= 1) {
        u64 o1 = __shfl_xor((unsigned long long)k1, mask, 64);
        u64 o2 = __shfl_xor((unsigned long long)k2, mask, 64);
        top2_merge(k1, k2, o1, o2);
    }
    u32 id1 = (u32)(k1 & 0xFFFFFFFFull);
    u32 id2 = (u32)(k2 & 0xFFFFFFFFull);

    const float* xr  = x  + (size_t)row * D_DIM + lane * 8;
    const float* c1p = cb + (size_t)id1 * D_DIM + lane * 8;
    const float* c2p = cb + (size_t)id2 * D_DIM + lane * 8;
    float4 xa = *(const float4*)xr,        xb = *(const float4*)(xr + 4);
    float4 p1a = *(const float4*)c1p,      p1b = *(const float4*)(c1p + 4);
    float4 p2a = *(const float4*)c2p,      p2b = *(const float4*)(c2p + 4);
    float xv[8] = {xa.x, xa.y, xa.z, xa.w, xb.x, xb.y, xb.z, xb.w};
    float v1[8] = {p1a.x, p1a.y, p1a.z, p1a.w, p1b.x, p1b.y, p1b.z, p1b.w};
    float v2[8] = {p2a.x, p2a.y, p2a.z, p2a.w, p2b.x, p2b.y, p2b.z, p2b.w};

    float s1 = 0.f, s2 = 0.f;
#pragma unroll
    for (int j = 0; j < 8; j++) {
        float d1 = xv[j] - v1[j]; s1 += d1 * d1;
        float d2 = xv[j] - v2[j]; s2 += d2 * d2;
    }
#pragma unroll
    for (int mask = 1; mask < 64; mask <<= 1) {
        s1 += __shfl_xor(s1, mask, 64);
        s2 += __shfl_xor(s2, mask, 64);
    }

    bool take2 = (s2 < s1) || (s2 == s1 && id2 < id1);  // tie -> smaller index (jnp.argmin)
    u32 idw = take2 ? id2 : id1;
    float sw = take2 ? s2 : s1;

    float ev[8];
#pragma unroll
    for (int j = 0; j < 8; j++) {
        float cj = take2 ? v2[j] : v1[j];
        ev[j] = xv[j] + (cj - xv[j]);   // replicate reference's x + (emb - x)
    }
    float* op = emb + (size_t)row * D_DIM + lane * 8;
    *(float4*)op       = (float4){ev[0], ev[1], ev[2], ev[3]};
    *(float4*)(op + 4) = (float4){ev[4], ev[5], ev[6], ev[7]};

    if (lane == 0) {
        idsf[row]  = (float)idw;
        lossf[row] = 1.25f * sw;   // emb_loss + 0.25*query_loss, both == ||x-emb||^2
    }
}

// ---------- launch ----------

extern "C" void kernel_launch(void* const* d_in, const int* in_sizes, int n_in,
                              void* d_out, int out_size, void* d_ws, size_t ws_size,
                              hipStream_t stream) {
    const float* x  = (const float*)d_in[0];
    const float* cb = (const float*)d_in[1];
    char* ws = (char*)d_ws;

    // workspace layout (bytes)
    u16*   xh      = (u16*)(ws + 0);                    // 32 MB
    u16*   xl      = (u16*)(ws + 33554432);             // 32 MB
    u16*   ch      = (u16*)(ws + 67108864);             //  8 MB
    u16*   cl      = (u16*)(ws + 75497472);             //  8 MB
    float* cnorm   = (float*)(ws + 83886080);           // 32 KB
    ulonglong2* tileres = (ulonglong2*)(ws + 83918848); // 32 MB  (total ~112 MB)

    float* emb   = (float*)d_out;
    float* idsf  = emb + (size_t)N_ROWS * D_DIM;
    float* lossf = idsf + N_ROWS;

    prep_split<<<dim3(K_CODES / 4), dim3(256), 0, stream>>>(cb, ch, cl, cnorm);
    prep_split<<<dim3(N_ROWS / 4),  dim3(256), 0, stream>>>(x, xh, xl, nullptr);
    qgemm<<<dim3((N_ROWS / BM) * (K_CODES / BN)), dim3(256), 0, stream>>>(xh, xl, ch, cl, cnorm, tileres);
    finalize<<<dim3(N_ROWS / 4), dim3(256), 0, stream>>>(x, cb, tileres, emb, idsf, lossf);
}

// Round 3
// 613.478 us; speedup vs baseline: 1.6758x; 1.6758x over previous
//
#include <hip/hip_runtime.h>
#include <stdint.h>

// Problem constants (fixed by setup_inputs)
#define N_ROWS  32768
#define D_DIM   512
#define K_CODES 8192
#define BM 128
#define BN 128
#define BK 64
#define NTILES (K_CODES / BN)   // 64 code-tiles per row

typedef __attribute__((ext_vector_type(8))) short short8;
typedef __attribute__((ext_vector_type(4))) float f32x4;
typedef unsigned long long u64;
typedef unsigned int u32;
typedef unsigned short u16;

// ---------- helpers ----------

__device__ __forceinline__ u16 bf_rne(float f) {
    // round-to-nearest-even fp32 -> bf16 (inputs are finite)
    u32 u = __float_as_uint(f);
    u32 r = (u + 0x7FFFu + ((u >> 16) & 1u)) >> 16;
    return (u16)r;
}

__device__ __forceinline__ u32 fkey(float f) {
    // monotonic (order-preserving) float -> uint transform
    u32 u = __float_as_uint(f);
    return (u & 0x80000000u) ? ~u : (u | 0x80000000u);
}

__device__ __forceinline__ void top2_merge(u64 &a1, u64 &a2, u64 b1, u64 b2) {
    u64 lo = a1 < b1 ? a1 : b1;
    u64 hi = a1 < b1 ? b1 : a1;
    u64 c  = a2 < b2 ? a2 : b2;
    a1 = lo;
    a2 = hi < c ? hi : c;
}

__device__ __forceinline__ void cswap(u64 &a, u64 &b) {
    u64 lo = a < b ? a : b;
    u64 hi = a < b ? b : a;
    a = lo; b = hi;
}

__device__ __forceinline__ void gll16(const void* g, void* l) {
    // async global->LDS, 16B per lane; LDS dest = wave-uniform base + lane*16
    __builtin_amdgcn_global_load_lds((const __attribute__((address_space(1))) void*)g,
                                     (__attribute__((address_space(3))) void*)l,
                                     16, 0, 0);
}

// ---------- prep: fp32 -> bf16 (RNE) + optional row sum-of-squares ----------

__global__ __launch_bounds__(256) void prep_bf16(const float* __restrict__ src,
                                                 u16* __restrict__ hp,
                                                 float* __restrict__ np) {
    int row  = blockIdx.x * 4 + (threadIdx.x >> 6);
    int lane = threadIdx.x & 63;
    const float* s = src + (size_t)row * D_DIM + lane * 8;
    float4 a = *(const float4*)(s);
    float4 b = *(const float4*)(s + 4);
    float v[8] = {a.x, a.y, a.z, a.w, b.x, b.y, b.z, b.w};
    short8 hv;
    float sum = 0.f;
#pragma unroll
    for (int j = 0; j < 8; j++) {
        hv[j] = (short)bf_rne(v[j]);
        sum += v[j] * v[j];
    }
    *(short8*)(hp + (size_t)row * D_DIM + lane * 8) = hv;
    if (np != nullptr) {
#pragma unroll
        for (int mask = 1; mask < 64; mask <<= 1)
            sum += __shfl_xor(sum, mask, 64);
        if (lane == 0) np[row] = sum;
    }
}

// ---------- main: bf16 GEMM (approx -2*x.c) + per-row top-2 over this 128-code tile ----------
// dist_approx(i,j) = cnorm[j] - 2 * (xh . ch)   -- candidate SELECTION only; finalize
// re-ranks the global top-4 in exact fp32, so bf16 rounding error is tolerated.
// Each block: 128 rows x 128 codes, writes (min1,id1,min2,id2) packed u64x2 per row.

__global__ __launch_bounds__(256, 2) void qgemm(const u16* __restrict__ xh,
                                                const u16* __restrict__ ch,
                                                const float* __restrict__ cnorm,
                                                ulonglong2* __restrict__ tileres) {
    // LDS: A [128 rows][64] bf16 = 16KB, B same -> 32KB total, single-buffered.
    __shared__ char smem[32768];

    // XCD-aware swizzle (16384 blocks % 8 == 0 -> simple remap is bijective).
    // tileM fastest within an XCD chunk -> 8 codebook tiles (1MB) stay L2-resident.
    int bid = blockIdx.x;
    int wg  = (bid & 7) * 2048 + (bid >> 3);
    int tileM = wg & 255;   // 0..255
    int tileN = wg >> 8;    // 0..63

    int tid  = threadIdx.x;
    int lane = tid & 63;
    int w    = tid >> 6;
    int wr   = w >> 1, wc = w & 1;   // wave -> 64x64 output quadrant

    f32x4 acc[4][4];
#pragma unroll
    for (int m = 0; m < 4; m++)
#pragma unroll
        for (int n = 0; n < 4; n++)
            acc[m][n] = (f32x4){0.f, 0.f, 0.f, 0.f};

    // Staging: 1024 16B-chunks per buffer; q = tid + 256*i; row=q>>3; chunk=q&7.
    // LDS written LINEARLY (global_load_lds constraint); XOR swizzle chunk^=(row&7)
    // applied on the GLOBAL source (rule #21: both-sides-or-neither). On the
    // ds_read side, bank-quad = chunk^(row&7): 16 consecutive rows cover all 8
    // quads twice -> 2 lanes/quad = free (m136).
    size_t aoff[4], boff[4];
    int ldsq[4];
#pragma unroll
    for (int i = 0; i < 4; i++) {
        int q   = tid + 256 * i;
        int row = q >> 3;
        int csw = (q & 7) ^ (row & 7);
        aoff[i] = ((size_t)(tileM * BM + row)) * D_DIM + csw * 8;
        boff[i] = ((size_t)(tileN * BN + row)) * D_DIM + csw * 8;
        ldsq[i] = (w * 64 + 256 * i) * 16;   // wave-uniform LDS byte base
    }

    for (int kk = 0; kk < D_DIM; kk += BK) {
#pragma unroll
        for (int i = 0; i < 4; i++) {
            gll16(xh + aoff[i] + kk, smem +     0 + ldsq[i]);
            gll16(ch + boff[i] + kk, smem + 16384 + ldsq[i]);
        }
        __syncthreads();   // compiler drains vmcnt before s_barrier

        int klo = (lane >> 4) * 16;   // byte offset of this lane-quad's 8 bf16 within a 32-k subtile
        short8 b[2][4];
#pragma unroll
        for (int t = 0; t < 2; t++)
#pragma unroll
            for (int n = 0; n < 4; n++) {
                int rb = wc * 64 + n * 16 + (lane & 15);
                int cbyte = t * 64 + klo;
                int ad = rb * 128 + (cbyte ^ ((rb & 7) << 4));
                b[t][n] = *(const short8*)(smem + 16384 + ad);
            }
#pragma unroll
        for (int m = 0; m < 4; m++) {
            int ra = wr * 64 + m * 16 + (lane & 15);
#pragma unroll
            for (int t = 0; t < 2; t++) {
                int cbyte = t * 64 + klo;
                int ad = ra * 128 + (cbyte ^ ((ra & 7) << 4));
                short8 a = *(const short8*)(smem + ad);
#pragma unroll
                for (int n = 0; n < 4; n++)
                    acc[m][n] = __builtin_amdgcn_mfma_f32_16x16x32_bf16(a, b[t][n], acc[m][n], 0, 0, 0);
            }
        }
        __syncthreads();
    }

    // ---- epilogue: dist + per-row top-2 across the 128 codes of this tile ----
    int cq = lane >> 4, cc = lane & 15;
    float cn[4];
#pragma unroll
    for (int n = 0; n < 4; n++)
        cn[n] = cnorm[tileN * BN + wc * 64 + n * 16 + cc];

    u64* sc = (u64*)smem;   // scratch [128 rows][2 wc][2] = 4KB (staging is dead now)

#pragma unroll
    for (int m = 0; m < 4; m++) {
#pragma unroll
        for (int r = 0; r < 4; r++) {
            u64 k1 = ~0ull, k2 = ~0ull;
#pragma unroll
            for (int n = 0; n < 4; n++) {
                float d = cn[n] - 2.0f * acc[m][n][r];
                u64 key = ((u64)fkey(d) << 32) | (u32)(tileN * BN + wc * 64 + n * 16 + cc);
                if (key < k1) { k2 = k1; k1 = key; }
                else if (key < k2) { k2 = key; }
            }
            // reduce across the 16 lanes sharing this row (C/D: col=lane&15)
#pragma unroll
            for (int mask = 1; mask < 16; mask <<= 1) {
                u64 o1 = __shfl_xor((unsigned long long)k1, mask, 16);
                u64 o2 = __shfl_xor((unsigned long long)k2, mask, 16);
                top2_merge(k1, k2, o1, o2);
            }
            if (cc == 0) {
                int rl = wr * 64 + m * 16 + cq * 4 + r;   // C/D: row=(lane>>4)*4+reg
                sc[rl * 4 + wc * 2 + 0] = k1;
                sc[rl * 4 + wc * 2 + 1] = k2;
            }
        }
    }
    __syncthreads();
    if (tid < 128) {
        u64 a1 = sc[tid * 4 + 0], a2 = sc[tid * 4 + 1];
        u64 b1 = sc[tid * 4 + 2], b2 = sc[tid * 4 + 3];
        top2_merge(a1, a2, b1, b2);
        ulonglong2 outv;
        outv.x = a1;   // sorted: x <= y
        outv.y = a2;
        tileres[(size_t)(tileM * BM + tid) * NTILES + tileN] = outv;
    }
}

// ---------- finalize: global top-4 merge, exact fp32 re-rank of 4 candidates,
//            gather emb (STE form), ids (as float), loss = 1.25 * ||x - emb||^2 ----------

__global__ __launch_bounds__(256) void finalize(const float* __restrict__ x, const float* __restrict__ cb,
                                                const ulonglong2* __restrict__ tileres,
                                                float* __restrict__ emb, float* __restrict__ idsf,
                                                float* __restrict__ lossf) {
    int row  = blockIdx.x * 4 + (threadIdx.x >> 6);
    int lane = threadIdx.x & 63;

    ulonglong2 t = tileres[(size_t)row * NTILES + lane];   // 64 tiles == 64 lanes
    // sorted 4-list per lane (keys unique: id in low bits)
    u64 k0 = t.x, k1 = t.y, k2 = ~0ull, k3 = ~0ull;
    // butterfly merge: lowest-4 of two sorted 4-lists via bitonic half-cleaner
#pragma unroll
    for (int mask = 1; mask < 64; mask <<= 1) {
        u64 p0 = __shfl_xor((unsigned long long)k0, mask, 64);
        u64 p1 = __shfl_xor((unsigned long long)k1, mask, 64);
        u64 p2 = __shfl_xor((unsigned long long)k2, mask, 64);
        u64 p3 = __shfl_xor((unsigned long long)k3, mask, 64);
        u64 m0 = k0 < p3 ? k0 : p3;
        u64 m1 = k1 < p2 ? k1 : p2;
        u64 m2 = k2 < p1 ? k2 : p1;
        u64 m3 = k3 < p0 ? k3 : p0;
        cswap(m0, m2); cswap(m1, m3); cswap(m0, m1); cswap(m2, m3);
        k0 = m0; k1 = m1; k2 = m2; k3 = m3;
    }
    u32 id0 = (u32)(k0 & 0xFFFFFFFFull);
    u32 id1 = (u32)(k1 & 0xFFFFFFFFull);
    u32 id2 = (u32)(k2 & 0xFFFFFFFFull);
    u32 id3 = (u32)(k3 & 0xFFFFFFFFull);

    const float* xr = x + (size_t)row * D_DIM + lane * 8;
    float4 xa = *(const float4*)xr, xb = *(const float4*)(xr + 4);
    float xv[8] = {xa.x, xa.y, xa.z, xa.w, xb.x, xb.y, xb.z, xb.w};

    const float* c0p = cb + (size_t)id0 * D_DIM + lane * 8;
    const float* c1p = cb + (size_t)id1 * D_DIM + lane * 8;
    const float* c2p = cb + (size_t)id2 * D_DIM + lane * 8;
    const float* c3p = cb + (size_t)id3 * D_DIM + lane * 8;
    float4 a0 = *(const float4*)c0p, b0 = *(const float4*)(c0p + 4);
    float4 a1 = *(const float4*)c1p, b1 = *(const float4*)(c1p + 4);
    float4 a2 = *(const float4*)c2p, b2 = *(const float4*)(c2p + 4);
    float4 a3 = *(const float4*)c3p, b3 = *(const float4*)(c3p + 4);
    float v0[8] = {a0.x, a0.y, a0.z, a0.w, b0.x, b0.y, b0.z, b0.w};
    float v1[8] = {a1.x, a1.y, a1.z, a1.w, b1.x, b1.y, b1.z, b1.w};
    float v2[8] = {a2.x, a2.y, a2.z, a2.w, b2.x, b2.y, b2.z, b2.w};
    float v3[8] = {a3.x, a3.y, a3.z, a3.w, b3.x, b3.y, b3.z, b3.w};

    float s0 = 0.f, s1 = 0.f, s2 = 0.f, s3 = 0.f;
#pragma unroll
    for (int j = 0; j < 8; j++) {
        float d0 = xv[j] - v0[j]; s0 += d0 * d0;
        float d1 = xv[j] - v1[j]; s1 += d1 * d1;
        float d2 = xv[j] - v2[j]; s2 += d2 * d2;
        float d3 = xv[j] - v3[j]; s3 += d3 * d3;
    }
#pragma unroll
    for (int mask = 1; mask < 64; mask <<= 1) {
        s0 += __shfl_xor(s0, mask, 64);
        s1 += __shfl_xor(s1, mask, 64);
        s2 += __shfl_xor(s2, mask, 64);
        s3 += __shfl_xor(s3, mask, 64);
    }

    // exact argmin over the 4 candidates; tie -> smaller index (jnp.argmin first-occurrence)
    float bs = s0; u32 bi = id0; int bj = 0;
    bool t1 = (s1 < bs) || (s1 == bs && id1 < bi); bs = t1 ? s1 : bs; bi = t1 ? id1 : bi; bj = t1 ? 1 : bj;
    bool t2 = (s2 < bs) || (s2 == bs && id2 < bi); bs = t2 ? s2 : bs; bi = t2 ? id2 : bi; bj = t2 ? 2 : bj;
    bool t3 = (s3 < bs) || (s3 == bs && id3 < bi); bs = t3 ? s3 : bs; bi = t3 ? id3 : bi; bj = t3 ? 3 : bj;

    float ev[8];
#pragma unroll
    for (int j = 0; j < 8; j++) {
        float cj = (bj == 0) ? v0[j] : (bj == 1) ? v1[j] : (bj == 2) ? v2[j] : v3[j];
        ev[j] = xv[j] + (cj - xv[j]);   // replicate reference's x + (emb - x)
    }
    float* op = emb + (size_t)row * D_DIM + lane * 8;
    *(float4*)op       = (float4){ev[0], ev[1], ev[2], ev[3]};
    *(float4*)(op + 4) = (float4){ev[4], ev[5], ev[6], ev[7]};

    if (lane == 0) {
        idsf[row]  = (float)bi;
        lossf[row] = 1.25f * bs;   // emb_loss + 0.25*query_loss, both == ||x-emb||^2
    }
}

// ---------- launch ----------

extern "C" void kernel_launch(void* const* d_in, const int* in_sizes, int n_in,
                              void* d_out, int out_size, void* d_ws, size_t ws_size,
                              hipStream_t stream) {
    const float* x  = (const float*)d_in[0];
    const float* cb = (const float*)d_in[1];
    char* ws = (char*)d_ws;

    // workspace layout (bytes)
    u16*   xh    = (u16*)(ws + 0);                      // 32 MB
    u16*   ch    = (u16*)(ws + 33554432);               //  8 MB
    float* cnorm = (float*)(ws + 41943040);             // 32 KB
    ulonglong2* tileres = (ulonglong2*)(ws + 41975808); // 32 MB (total ~74 MB)

    float* emb   = (float*)d_out;
    float* idsf  = emb + (size_t)N_ROWS * D_DIM;
    float* lossf = idsf + N_ROWS;

    prep_bf16<<<dim3(K_CODES / 4), dim3(256), 0, stream>>>(cb, ch, cnorm);
    prep_bf16<<<dim3(N_ROWS / 4),  dim3(256), 0, stream>>>(x, xh, nullptr);
    qgemm<<<dim3((N_ROWS / BM) * (K_CODES / BN)), dim3(256), 0, stream>>>(xh, ch, cnorm, tileres);
    finalize<<<dim3(N_ROWS / 4), dim3(256), 0, stream>>>(x, cb, tileres, emb, idsf, lossf);
}